// Round 5
// baseline (4357.586 us; speedup 1.0000x reference)
//
#include <hip/hip_runtime.h>
#include <stdint.h>

// The np reference was generated with XLA-CPU-style FP contraction: the LIF
// recurrence MUST be fmaf(alpha, v, i) — verified bit-exact in round 4's
// designed experiment (separate mul/add flips 1-2 of 26.2M l1 decisions).
#pragma clang fp contract(off)

#define BB 128
#define TT 100
#define NN 2048
#define OO 512
#define DLY 10

#define ALPHA_F 0.90483741803595952f
#define DEC_F   0.95122942450071403f
#define OMD_F   0.048770575499285966f
#define A_P 1e-4f
#define A_M 1e-4f
#define THRV 0.02f
#define INVB 0.0078125f   // 1/128 exact

// ---- workspace layout (bytes) ----
#define OFF_MASK   ((size_t)0)          // u64 [BB][TT][32]  l1 spike bitmasks
#define OFF_HWT    ((size_t)3276800)    // f32 [NN][OO]      hw transposed
#define OFF_IEWT   ((size_t)7471104)    // f32 [OO][OO]      iew transposed, diag-masked
#define OFF_TR1    ((size_t)8519680)    // f32 [BB][NN]
#define OFF_TR2    ((size_t)9568256)    // f32 [BB][OO]
#define OFF_TRI    ((size_t)9830400)    // f32 [BB][OO]
#define OFF_V2     ((size_t)10092544)   // f32 [BB][OO]
#define OFF_VI     ((size_t)10354688)   // f32 [BB][OO]
#define OFF_BUF    ((size_t)10616832)   // f32 [BB][DLY][OO]
#define OFF_EIWD   ((size_t)13238272)   // f32 [OO]          eiw diagonal
#define OFF_ML2    ((size_t)13240320)   // f32 [2][OO]  sum_b l2 (exact ints)
#define OFF_MINH   ((size_t)13244416)   // f32 [2][OO]  sum_b inh
#define OFF_MTR2S  ((size_t)13248512)   // f32 [2][OO]  mean(tr2) state
#define OFF_MTRIS  ((size_t)13252608)   // f32 [2][OO]  mean(tri) state
#define OFF_COLS   ((size_t)13256704)   // f32 [2][OO]  column sums of iewT
#define OFF_FLAGS  ((size_t)13260800)   // u32 [4]: 0=anyL2spike
#define WS_NEED    ((size_t)13260816)

#define PTRS(ws) \
  unsigned long long* mask = (unsigned long long*)((ws) + OFF_MASK); \
  float* hwT  = (float*)((ws) + OFF_HWT);  \
  float* iewT = (float*)((ws) + OFF_IEWT); \
  float* tr1  = (float*)((ws) + OFF_TR1);  \
  float* tr2  = (float*)((ws) + OFF_TR2);  \
  float* tri  = (float*)((ws) + OFF_TRI);  \
  float* v2   = (float*)((ws) + OFF_V2);   \
  float* vi   = (float*)((ws) + OFF_VI);   \
  float* buf  = (float*)((ws) + OFF_BUF);  \
  float* eiwd = (float*)((ws) + OFF_EIWD); \
  float* ml2  = (float*)((ws) + OFF_ML2);  \
  float* minh = (float*)((ws) + OFF_MINH); \
  float* m2s  = (float*)((ws) + OFF_MTR2S);\
  float* m3s  = (float*)((ws) + OFF_MTRIS);\
  float* cols = (float*)((ws) + OFF_COLS); \
  unsigned* flags = (unsigned*)((ws) + OFF_FLAGS); \
  (void)mask;(void)hwT;(void)iewT;(void)tr1;(void)tr2;(void)tri;(void)v2;(void)vi; \
  (void)buf;(void)eiwd;(void)ml2;(void)minh;(void)m2s;(void)m3s;(void)cols;(void)flags;

// Zero the flag words before kA (ws arrives poisoned 0xAA).
__global__ void kZ(uint8_t* __restrict__ ws) {
  PTRS(ws);
  if (threadIdx.x < 4) flags[threadIdx.x] = 0u;
}

// ---------------------------------------------------------------------------
// Kernel A: full l1/v1 path for all t (weight-independent) with the verified
// FMA recurrence; spike bitmasks; all workspace init.
// ---------------------------------------------------------------------------
__global__ __launch_bounds__(256) void kA(
    const float* __restrict__ x, const float* __restrict__ w_in,
    const float* __restrict__ hid, const float* __restrict__ eiw_in,
    const float* __restrict__ iew_in, float* __restrict__ out,
    uint8_t* __restrict__ ws)
{
#pragma clang fp contract(off)
  const int bx = blockIdx.x, tid = threadIdx.x;
  PTRS(ws);

  if (bx < 1024) {
    const int b = bx >> 3;
    const int n = ((bx & 7) << 8) + tid;
    const float wd = w_in[(size_t)n * NN + n];      // input_weight diagonal
    const float* xp = x + ((size_t)b * TT) * NN + n;
    float* op = out + ((size_t)b * TT) * NN + n;
    const int word = n >> 6;
    const bool lane0 = ((tid & 63) == 0);
    float v = 0.f;
    for (int t = 0; t < TT; ++t) {
      float xv = xp[(size_t)t * NN];
      float iv = wd * xv;              // exact f32 product (einsum row has 1 nonzero)
      v = fmaf(ALPHA_F, v, iv);        // bit-exact vs np ref (round-4 experiment)
      bool s = (v > THRV);
      op[(size_t)t * NN] = s ? 1.f : 0.f;
      if (s) v = 0.f;                  // hard reset
      unsigned long long m = __ballot(s);
      if (lane0) mask[((size_t)b * TT + t) * 32 + word] = m;
    }
  } else {
    const int idx = (bx - 1024) * 256 + tid;        // 0..262143
    #pragma unroll
    for (int k = 0; k < 4; ++k) {                   // hwT[n][q] = hid[q][n]
      int e = idx + k * 262144;
      int n = e & (NN - 1);
      int q = e >> 11;
      hwT[(size_t)n * OO + q] = hid[(size_t)q * NN + n];
    }
    { int p = idx >> 9, q = idx & (OO - 1);         // iewT[p][q] = iew[q][p], diag 0
      iewT[idx] = (p == q) ? 0.f : iew_in[(size_t)q * OO + p]; }
    tr1[idx] = 0.f;
    if (idx < BB * OO) { tr2[idx]=0.f; tri[idx]=0.f; v2[idx]=0.f; vi[idx]=0.f; }
    #pragma unroll
    for (int k = 0; k < 3; ++k) { int e = idx + k * 262144; if (e < BB*DLY*OO) buf[e]=0.f; }
    if (idx < OO) eiwd[idx] = eiw_in[(size_t)idx * OO + idx];
    if (idx < 2*OO) { ml2[idx]=0.f; minh[idx]=0.f; m2s[idx]=0.f; m3s[idx]=0.f; }
    if (idx < OO) {                                 // cols slot0 = masked row-sums of iew_in
      float sacc = 0.f;
      for (int p = 0; p < OO; ++p) if (p != idx) sacc += iew_in[(size_t)idx * OO + p];
      cols[idx] = sacc; cols[OO + idx] = 0.f;
    }
  }
}

// ---------------------------------------------------------------------------
// K1(t): blocks [0,128): per-batch O-path (sparse l1v, inh_out, l2, inh, buf,
//        tr2/tri, exact binary means). blocks [128,256): tr1 update.
// ---------------------------------------------------------------------------
__global__ __launch_bounds__(512) void kStep1(
    const int* __restrict__ train_p, float* __restrict__ out,
    uint8_t* __restrict__ ws, int t)
{
#pragma clang fp contract(off)
  const int bx = blockIdx.x, tid = threadIdx.x;
  const int s = t & 1, tm = t % DLY;
  PTRS(ws);
  const int train = *train_p;
  const int se = train ? s : 0;   // eval: cols never cycles, use slot 0

  if (bx < BB) {
    __shared__ unsigned long long sm[32];
    __shared__ int sidx[NN];
    __shared__ short szer[OO];
    __shared__ int scnt, zcnt, anyc;
    const int b = bx, q = tid;
    if (tid == 0) { scnt = 0; zcnt = 0; anyc = 0; }
    if (tid < 32) sm[tid] = mask[((size_t)b * TT + t) * 32 + tid];
    float bv = buf[((size_t)b * DLY + tm) * OO + q];
    float c = cols[se * OO + q];
    __syncthreads();
    if (c != 0.f) anyc = 1;
    #pragma unroll
    for (int k = 0; k < 4; ++k) {                   // compact spiking-n list
      int n = (k << 9) + tid;
      if ((sm[n >> 6] >> (n & 63)) & 1ull) { int pos = atomicAdd(&scnt, 1); sidx[pos] = n; }
    }
    if (bv == 0.f) { int pz = atomicAdd(&zcnt, 1); szer[pz] = (short)q; }
    if (train && bx == 0) {                         // cycle double-buffered slots
      cols[(s ^ 1) * OO + q] = 0.f;
      ml2 [(s ^ 1) * OO + q] = 0.f;
      minh[(s ^ 1) * OO + q] = 0.f;
    }
    __syncthreads();
    // l1v[b,q] = sum over spiking n of hwT[n][q]  (robust path: order-free)
    float l1v = 0.f;
    { const int cnt = scnt;
      int k = 0;
      for (; k + 4 <= cnt; k += 4) {
        int n0=sidx[k], n1=sidx[k+1], n2=sidx[k+2], n3=sidx[k+3];
        float h0=hwT[(size_t)n0*OO+q], h1=hwT[(size_t)n1*OO+q];
        float h2=hwT[(size_t)n2*OO+q], h3=hwT[(size_t)n3*OO+q];
        l1v += h0; l1v += h1; l1v += h2; l1v += h3;
      }
      for (; k < cnt; ++k) l1v += hwT[(size_t)sidx[k]*OO+q];
    }
    if (!train) l1v = 0.2f * l1v;
    // inh_out = colsum - sum over buf==0 rows (exactly 0 while iew == 0)
    float inh_o = 0.f;
    if (anyc) {
      float acc = c; const int zc = zcnt;
      int k = 0;
      for (; k + 4 <= zc; k += 4) {
        int p0=szer[k], p1=szer[k+1], p2=szer[k+2], p3=szer[k+3];
        acc -= iewT[(size_t)p0*OO+q]; acc -= iewT[(size_t)p1*OO+q];
        acc -= iewT[(size_t)p2*OO+q]; acc -= iewT[(size_t)p3*OO+q];
      }
      for (; k < zc; ++k) acc -= iewT[(size_t)szer[k]*OO+q];
      inh_o = acc;
    }
    // l2 neuron (FMA recurrence; margins robust)
    const int bq = b * OO + q;
    float i2  = l1v - inh_o;
    float v2v = fmaf(ALPHA_F, v2[bq], i2);
    bool l2 = (v2v > THRV);
    v2[bq] = l2 ? 0.f : v2v;
    out[(size_t)BB*TT*NN + ((size_t)b * TT + t) * OO + q] = l2 ? 1.f : 0.f;
    // inh neuron: inh_in = l2 * eiw_diag[q] (exact; eiw diag-masked each step)
    float ii  = l2 ? eiwd[q] : 0.f;
    float viv = fmaf(ALPHA_F, vi[bq], ii);
    bool ih = (viv > THRV);
    vi[bq] = ih ? 0.f : viv;
    buf[((size_t)b * DLY + tm) * OO + q] = ih ? 1.f : 0.f;
    if (train) {
      float l2f = l2 ? 1.f : 0.f, ihf = ih ? 1.f : 0.f;
      float d2 = DEC_F * tr2[bq]; tr2[bq] = d2 + OMD_F * l2f;
      float d3 = DEC_F * tri[bq]; tri[bq] = d3 + OMD_F * ihf;
      if (l2) { atomicAdd(&ml2[s * OO + q], 1.f); flags[0] = 1u; }  // exact int sums
      if (ih) { atomicAdd(&minh[s * OO + q], 1.f); }
    }
  } else {
    // tr1 update for batch b (sole writer; K2 reads afterwards)
    const int b = bx - BB;
    if (train) {
      const float* lp = out + ((size_t)b * TT + t) * NN;
      float* tp = tr1 + (size_t)b * NN;
      #pragma unroll
      for (int k = 0; k < 4; ++k) {
        int n = (k << 9) + tid;
        float d = DEC_F * tp[n];
        tp[n] = d + OMD_F * lp[n];
      }
    }
  }
}

// ---------------------------------------------------------------------------
// K2(t): blocks [0,256): hw (O x N) rank-128 STDP update, tiled 64x64.
//        blocks [256,320): iew (O x O) update + next-step column sums.
//        block 320: eiw diagonal + mean-state cycling.
// ---------------------------------------------------------------------------
__global__ __launch_bounds__(256) void kStep2(
    const int* __restrict__ train_p, uint8_t* __restrict__ ws, int t)
{
#pragma clang fp contract(off)
  const int bx = blockIdx.x, tid = threadIdx.x;
  const int s = t & 1;
  PTRS(ws);
  if (!*train_p) return;

  if (bx < 320) {
    if (!flags[0]) return;                 // no l2 spike yet => tr2 == 0 => no-op
    const bool isHW = (bx < 256);
    const int e  = isHW ? bx : (bx - 256);
    const int pt = e >> 3, qt = e & 7;
    __shared__ float s1[BB * 64];
    __shared__ float s2[BB * 64];
    const float* Apre = isHW ? tr1 : tri;  // pre-trace slab
    const int preStride = isHW ? NN : OO;
    for (int it = 0; it < 32; ++it) {
      int ee = it * 256 + tid;
      int b = ee >> 6, i = ee & 63;
      s1[ee] = Apre[(size_t)b * preStride + pt * 64 + i];
      s2[ee] = tr2[b * OO + qt * 64 + i];
    }
    __syncthreads();
    const int tp = tid >> 4, tq = tid & 15;
    float acc[4][4] = {{0.f,0.f,0.f,0.f},{0.f,0.f,0.f,0.f},{0.f,0.f,0.f,0.f},{0.f,0.f,0.f,0.f}};
    for (int b = 0; b < BB; ++b) {
      float4 av = *(const float4*)&s1[b * 64 + tp * 4];
      float4 cv = *(const float4*)&s2[b * 64 + tq * 4];
      acc[0][0] = fmaf(av.x, cv.x, acc[0][0]);
      acc[0][1] = fmaf(av.x, cv.y, acc[0][1]);
      acc[0][2] = fmaf(av.x, cv.z, acc[0][2]);
      acc[0][3] = fmaf(av.x, cv.w, acc[0][3]);
      acc[1][0] = fmaf(av.y, cv.x, acc[1][0]);
      acc[1][1] = fmaf(av.y, cv.y, acc[1][1]);
      acc[1][2] = fmaf(av.y, cv.z, acc[1][2]);
      acc[1][3] = fmaf(av.y, cv.w, acc[1][3]);
      acc[2][0] = fmaf(av.z, cv.x, acc[2][0]);
      acc[2][1] = fmaf(av.z, cv.y, acc[2][1]);
      acc[2][2] = fmaf(av.z, cv.z, acc[2][2]);
      acc[2][3] = fmaf(av.z, cv.w, acc[2][3]);
      acc[3][0] = fmaf(av.w, cv.x, acc[3][0]);
      acc[3][1] = fmaf(av.w, cv.y, acc[3][1]);
      acc[3][2] = fmaf(av.w, cv.z, acc[3][2]);
      acc[3][3] = fmaf(av.w, cv.w, acc[3][3]);
    }
    float mq[4];
    #pragma unroll
    for (int j = 0; j < 4; ++j) {          // mean(tr2_t) via exact binary-spike recurrence
      int q = qt * 64 + tq * 4 + j;
      mq[j] = DEC_F * m2s[s * OO + q] + OMD_F * (ml2[s * OO + q] * INVB);
    }
    if (isHW) {
      #pragma unroll
      for (int i = 0; i < 4; ++i) {
        size_t p = (size_t)(pt * 64 + tp * 4 + i);
        #pragma unroll
        for (int j = 0; j < 4; ++j) {
          int q = qt * 64 + tq * 4 + j;
          float* hp = &hwT[p * OO + q];
          float old = *hp;
          *hp = old + (A_P * (acc[i][j] * INVB) - A_M * old * mq[j]);
        }
      }
    } else {
      float csum[4] = {0.f,0.f,0.f,0.f};
      #pragma unroll
      for (int i = 0; i < 4; ++i) {
        int p = pt * 64 + tp * 4 + i;
        #pragma unroll
        for (int j = 0; j < 4; ++j) {
          int q = qt * 64 + tq * 4 + j;
          float* wp = &iewT[(size_t)p * OO + q];
          float old = *wp;
          float nv = (p == q) ? 0.f
                              : (old + (A_P * (acc[i][j] * INVB) - A_M * old * mq[j]));
          *wp = nv;
          csum[j] += nv;
        }
      }
      #pragma unroll
      for (int j = 0; j < 4; ++j)
        atomicAdd(&cols[(s ^ 1) * OO + (qt * 64 + tq * 4 + j)], csum[j]);
    }
  } else {
    // block 320: eiw diagonal + mean-state slot cycling (runs every step)
    for (int k = 0; k < 2; ++k) {
      int q = k * 256 + tid;
      float m2v = DEC_F * m2s[s*OO+q] + OMD_F * (ml2[s*OO+q] * INVB);
      float m3v = DEC_F * m3s[s*OO+q] + OMD_F * (minh[s*OO+q] * INVB);
      m2s[(s^1)*OO+q] = m2v;
      m3s[(s^1)*OO+q] = m3v;
      float hd = 0.f;
      for (int b = 0; b < BB; ++b) hd = fmaf(tri[b*OO+q], tr2[b*OO+q], hd);
      hd *= INVB;
      float old = eiwd[q];
      eiwd[q] = old + (A_P * hd - A_M * old * m3v);
    }
  }
}

extern "C" void kernel_launch(void* const* d_in, const int* in_sizes, int n_in,
                              void* d_out, int out_size, void* d_ws, size_t ws_size,
                              hipStream_t stream) {
  const float* x     = (const float*)d_in[0];
  const float* w_in  = (const float*)d_in[1];
  const float* hid   = (const float*)d_in[2];
  const float* eiw   = (const float*)d_in[3];
  const float* iew   = (const float*)d_in[4];
  const int*   train = (const int*)d_in[5];
  float* out = (float*)d_out;
  uint8_t* ws = (uint8_t*)d_ws;
  (void)in_sizes; (void)n_in; (void)out_size; (void)ws_size;

  hipLaunchKernelGGL(kZ, dim3(1), dim3(64), 0, stream, ws);
  hipLaunchKernelGGL(kA, dim3(2048), dim3(256), 0, stream, x, w_in, hid, eiw, iew, out, ws);
  for (int t = 0; t < TT; ++t) {
    hipLaunchKernelGGL(kStep1, dim3(256), dim3(512), 0, stream, train, out, ws, t);
    hipLaunchKernelGGL(kStep2, dim3(321), dim3(256), 0, stream, train, ws, t);
  }
}